// Round 7
// baseline (386.598 us; speedup 1.0000x reference)
//
#include <hip/hip_runtime.h>

#define D 64
// BUCKET_SHIFT 9 (512 rows/bucket): binA run length = chunk/nbuck ~28 edges,
// low partial-line write amp -- the measured binA bottleneck (R11: shorter
// runs raised WRITE_SIZE 51.7->64.4MB and dur 64.9->71us despite 2x
// occupancy; VALUBusy stayed 1.5%. Time tracks run length, not occupancy).
#define BUCKET_SHIFT 9
#define ROWS_PER_BUCKET 512
#define NBUCK_MAX 1024
#define BINA_CHUNK 8192
#define BINA_THREADS 512
// key packing in tmp: [lr:13][col:19] in low u32 (lr<=511, col<2^19 since
// NBUCK_MAX*512 = 2^19 bounds N on this path), val f32 in high u32.
#define COL_BITS 19
#define COL_MASK ((1u << COL_BITS) - 1u)

typedef unsigned int u32;
typedef unsigned long long u64;

static inline char* align16(char* p) {
    return (char*)(((uintptr_t)p + 15) & ~(uintptr_t)15);
}

// bf16x2 helpers (packed pair in one u32; low ushort = even element)
__device__ __forceinline__ float bflo(u32 p) { return __uint_as_float(p << 16); }
__device__ __forceinline__ float bfhi(u32 p) { return __uint_as_float(p & 0xFFFF0000u); }
__device__ __forceinline__ u32 pack_bf16x2(float a, float b) {
    u32 ua = __float_as_uint(a);
    u32 ub = __float_as_uint(b);
    ua = (ua + 0x7FFFu + ((ua >> 16) & 1u)) >> 16;   // RNE
    ub = (ub + 0x7FFFu + ((ub >> 16) & 1u)) >> 16;
    return ua | (ub << 16);
}

// R15: non-temporal edge loads -- the edge stream (19.2MB/pass, read once)
// was churning the 4MB/XCD L2 that the gather table needs for reuse.
__device__ __forceinline__ u64 nt_load_u64(const u64* p) {
    return __builtin_nontemporal_load(p);
}

// ---------------- init ----------------

__global__ void lg_to_bf16(const float4* __restrict__ user, const float4* __restrict__ item,
                           uint2* __restrict__ dst, int user_vec4, int total_vec4) {
    int i = blockIdx.x * blockDim.x + threadIdx.x;
    if (i >= total_vec4) return;
    float4 v = (i < user_vec4) ? user[i] : item[i - user_vec4];
    dst[i] = make_uint2(pack_bf16x2(v.x, v.y), pack_bf16x2(v.z, v.w));
}

// ---------------- two-level bucket sort ----------------
// R13: no global pre-histogram/pre-scan. Each bucket gets a fixed-capacity
// slab in tmp (cap = avg + 1024 ~ 11 sigma for uniform-random rows); binA
// reserves runs with b*cap + atomicAdd directly. lg_cscan (1 tiny block)
// then scans the resulting counts into CSR bucket bases for binB2.

// Pass A: LDS hist -> one global atomic per (block,bucket) to reserve a run
// in the bucket's slab -> direct global scatter. Chunk 8192 (293 blocks ~
// 1.14/CU): keep runs long (see BUCKET_SHIFT note).
__global__ void lg_binA(const int* __restrict__ rows, const int* __restrict__ cols,
                        const float* __restrict__ vals, int* __restrict__ bucketCursor,
                        u64* __restrict__ tmp, int nnz, int nbuck, int cap) {
    __shared__ int hist[NBUCK_MAX];
    __shared__ int base[NBUCK_MAX];
    int tid = threadIdx.x;
    int bstart = blockIdx.x * BINA_CHUNK;
    int bend = min(bstart + BINA_CHUNK, nnz);

    for (int i = tid; i < nbuck; i += BINA_THREADS) hist[i] = 0;
    __syncthreads();
    for (int e = bstart + tid; e < bend; e += BINA_THREADS)
        atomicAdd(&hist[rows[e] >> BUCKET_SHIFT], 1);
    __syncthreads();
    for (int b = tid; b < nbuck; b += BINA_THREADS) {
        int c = hist[b];
        base[b] = (c > 0) ? (b * cap + atomicAdd(&bucketCursor[b], c)) : 0;
        hist[b] = 0;   // reuse as local cursor
    }
    __syncthreads();
    for (int e = bstart + tid; e < bend; e += BINA_THREADS) {
        int r = rows[e];
        int b = r >> BUCKET_SHIFT;
        int pos = base[b] + atomicAdd(&hist[b], 1);
        // overflow tripwire: never taken for uniform-random rows (11 sigma);
        // guards memory safety -- an overflow drops edges => loud absmax fail.
        if (pos < (b + 1) * cap) {
            u32 key = ((u32)(r & (ROWS_PER_BUCKET - 1)) << COL_BITS) | (u32)cols[e];
            u64 packed = (u64)key | ((u64)__float_as_uint(vals[e]) << 32);
            tmp[pos] = packed;
        }
    }
}

// Tiny scan over per-bucket counts -> CSR bucket bases. 1 block.
__global__ void lg_cscan(const int* __restrict__ bucketCursor, int* __restrict__ bucketOffs,
                         int* __restrict__ offsets_end, int nbuck, int cap) {
    __shared__ int s[1024];
    int t = threadIdx.x;
    int v = (t < nbuck) ? min(bucketCursor[t], cap) : 0;
    s[t] = v;
    __syncthreads();
    #pragma unroll
    for (int off = 1; off < 1024; off <<= 1) {
        int x = (t >= off) ? s[t - off] : 0;
        __syncthreads();
        s[t] += x;
        __syncthreads();
    }
    if (t < nbuck) bucketOffs[t] = s[t] - v;
    if (t == 1023) {
        bucketOffs[nbuck] = s[1023];
        *offsets_end = s[1023];
    }
}

// Pass B2: one block per bucket (512 rows); per-row hist+scan in LDS ->
// emits final per-row CSR offsets and scatters edges into CSR order
// (L2-local 64KB window, single-writer lines -> low write amp).
__global__ void lg_binB2(const int* __restrict__ bucketCursor, const int* __restrict__ bucketOffs,
                         const u64* __restrict__ tmp,
                         int* __restrict__ offsets, int2* __restrict__ edges, int n, int cap) {
    __shared__ int h[ROWS_PER_BUCKET];
    __shared__ int s[ROWS_PER_BUCKET];
    __shared__ int cur[ROWS_PER_BUCKET];
    int bucket = blockIdx.x;
    int row0 = bucket << BUCKET_SHIFT;
    int tid = threadIdx.x;
    size_t tbase = (size_t)bucket * (size_t)cap;
    int cnt = min(bucketCursor[bucket], cap);
    int cbase = bucketOffs[bucket];

    h[tid] = 0;
    __syncthreads();
    for (int e = tid; e < cnt; e += 512)
        atomicAdd(&h[(u32)((u32)tmp[tbase + e]) >> COL_BITS], 1);
    __syncthreads();
    int v = h[tid];
    s[tid] = v;
    __syncthreads();
    #pragma unroll
    for (int off = 1; off < 512; off <<= 1) {
        int x = (tid >= off) ? s[tid - off] : 0;
        __syncthreads();
        s[tid] += x;
        __syncthreads();
    }
    int rowOff = cbase + s[tid] - v;
    int r = row0 + tid;
    if (r < n) offsets[r] = rowOff;
    cur[tid] = rowOff;
    __syncthreads();
    for (int e = tid; e < cnt; e += 512) {
        u64 p = tmp[tbase + e];
        u32 key = (u32)p;
        int lr = key >> COL_BITS;
        int col = (int)(key & COL_MASK);
        int pos = atomicAdd(&cur[lr], 1);
        edges[pos] = make_int2(col, (int)(u32)(p >> 32));
    }
}

// ---------------- fallback CSR build ----------------

__global__ void lg_hist(const int* __restrict__ rows, int* __restrict__ counts, int nnz) {
    int e = blockIdx.x * blockDim.x + threadIdx.x;
    if (e >= nnz) return;
    atomicAdd(&counts[rows[e]], 1);
}

__global__ void lg_scan1(const int* __restrict__ counts, int* __restrict__ offsets,
                         int* __restrict__ cursor, int n) {
    const int T = 1024;
    int t = threadIdx.x;
    int chunk = (n + T - 1) / T;
    int start = t * chunk;
    int end = min(start + chunk, n);
    int sum = 0;
    for (int i = start; i < end; ++i) sum += counts[i];
    __shared__ int sdata[T];
    sdata[t] = sum;
    __syncthreads();
    #pragma unroll
    for (int off = 1; off < T; off <<= 1) {
        int v = (t >= off) ? sdata[t - off] : 0;
        __syncthreads();
        sdata[t] += v;
        __syncthreads();
    }
    int offset = sdata[t] - sum;
    for (int i = start; i < end; ++i) {
        int c = counts[i];
        offsets[i] = offset;
        cursor[i] = offset;
        offset += c;
    }
    if (t == T - 1) offsets[n] = sdata[T - 1];
}

__global__ void lg_fill(const int* __restrict__ rows, const int* __restrict__ cols,
                        const float* __restrict__ vals, int* __restrict__ cursor,
                        u64* __restrict__ edges, int nnz) {
    int e = blockIdx.x * blockDim.x + threadIdx.x;
    if (e >= nnz) return;
    int pos = atomicAdd(&cursor[rows[e]], 1);
    u64 packed = (u64)(u32)cols[e] | ((u64)__float_as_uint(vals[e]) << 32);
    edges[pos] = packed;
}

// ---------------- pull SpMM (bf16 gather, fp32 accumulate) ----------------
// R10: one 16-lane sub-group owns one full row (lane q = dims 4q..4q+3).
// R11: main loop unroll 8: eight independent random gathers in flight.
// R14 FAILED (predicated rounds, +6us: per-round cmp/cndmask on the address
// path broke 8-wide load clauses); R15 reverts to the proven 8/4/1 tails and
// adds NT edge loads (stream-once data, keep L2 for the gather table).

__global__ void lg_pull_bf16(const int* __restrict__ offs, const int2* __restrict__ edges,
                             const u32* __restrict__ src,
                             u32* __restrict__ nxt, int n) {
    int row = blockIdx.x * 16 + (threadIdx.x >> 4);
    if (row >= n) return;
    int q = threadIdx.x & 15;
    const u64* ep = (const u64*)edges;

    int beg = offs[row];
    int end = offs[row + 1];
    float4 acc = make_float4(0.f, 0.f, 0.f, 0.f);

    int j = beg;
    for (; j + 8 <= end; j += 8) {
        u64 e0 = nt_load_u64(ep + j + 0);
        u64 e1 = nt_load_u64(ep + j + 1);
        u64 e2 = nt_load_u64(ep + j + 2);
        u64 e3 = nt_load_u64(ep + j + 3);
        u64 e4 = nt_load_u64(ep + j + 4);
        u64 e5 = nt_load_u64(ep + j + 5);
        u64 e6 = nt_load_u64(ep + j + 6);
        u64 e7 = nt_load_u64(ep + j + 7);
        uint2 g0 = ((const uint2*)(src + (size_t)(u32)e0 * 32))[q];
        uint2 g1 = ((const uint2*)(src + (size_t)(u32)e1 * 32))[q];
        uint2 g2 = ((const uint2*)(src + (size_t)(u32)e2 * 32))[q];
        uint2 g3 = ((const uint2*)(src + (size_t)(u32)e3 * 32))[q];
        uint2 g4 = ((const uint2*)(src + (size_t)(u32)e4 * 32))[q];
        uint2 g5 = ((const uint2*)(src + (size_t)(u32)e5 * 32))[q];
        uint2 g6 = ((const uint2*)(src + (size_t)(u32)e6 * 32))[q];
        uint2 g7 = ((const uint2*)(src + (size_t)(u32)e7 * 32))[q];
        float v0 = __uint_as_float((u32)(e0 >> 32));
        float v1 = __uint_as_float((u32)(e1 >> 32));
        float v2 = __uint_as_float((u32)(e2 >> 32));
        float v3 = __uint_as_float((u32)(e3 >> 32));
        float v4 = __uint_as_float((u32)(e4 >> 32));
        float v5 = __uint_as_float((u32)(e5 >> 32));
        float v6 = __uint_as_float((u32)(e6 >> 32));
        float v7 = __uint_as_float((u32)(e7 >> 32));
        acc.x += v0 * bflo(g0.x) + v1 * bflo(g1.x) + v2 * bflo(g2.x) + v3 * bflo(g3.x)
               + v4 * bflo(g4.x) + v5 * bflo(g5.x) + v6 * bflo(g6.x) + v7 * bflo(g7.x);
        acc.y += v0 * bfhi(g0.x) + v1 * bfhi(g1.x) + v2 * bfhi(g2.x) + v3 * bfhi(g3.x)
               + v4 * bfhi(g4.x) + v5 * bfhi(g5.x) + v6 * bfhi(g6.x) + v7 * bfhi(g7.x);
        acc.z += v0 * bflo(g0.y) + v1 * bflo(g1.y) + v2 * bflo(g2.y) + v3 * bflo(g3.y)
               + v4 * bflo(g4.y) + v5 * bflo(g5.y) + v6 * bflo(g6.y) + v7 * bflo(g7.y);
        acc.w += v0 * bfhi(g0.y) + v1 * bfhi(g1.y) + v2 * bfhi(g2.y) + v3 * bfhi(g3.y)
               + v4 * bfhi(g4.y) + v5 * bfhi(g5.y) + v6 * bfhi(g6.y) + v7 * bfhi(g7.y);
    }
    for (; j + 4 <= end; j += 4) {
        u64 e0 = nt_load_u64(ep + j + 0);
        u64 e1 = nt_load_u64(ep + j + 1);
        u64 e2 = nt_load_u64(ep + j + 2);
        u64 e3 = nt_load_u64(ep + j + 3);
        uint2 g0 = ((const uint2*)(src + (size_t)(u32)e0 * 32))[q];
        uint2 g1 = ((const uint2*)(src + (size_t)(u32)e1 * 32))[q];
        uint2 g2 = ((const uint2*)(src + (size_t)(u32)e2 * 32))[q];
        uint2 g3 = ((const uint2*)(src + (size_t)(u32)e3 * 32))[q];
        float v0 = __uint_as_float((u32)(e0 >> 32));
        float v1 = __uint_as_float((u32)(e1 >> 32));
        float v2 = __uint_as_float((u32)(e2 >> 32));
        float v3 = __uint_as_float((u32)(e3 >> 32));
        acc.x += v0 * bflo(g0.x) + v1 * bflo(g1.x) + v2 * bflo(g2.x) + v3 * bflo(g3.x);
        acc.y += v0 * bfhi(g0.x) + v1 * bfhi(g1.x) + v2 * bfhi(g2.x) + v3 * bfhi(g3.x);
        acc.z += v0 * bflo(g0.y) + v1 * bflo(g1.y) + v2 * bflo(g2.y) + v3 * bflo(g3.y);
        acc.w += v0 * bfhi(g0.y) + v1 * bfhi(g1.y) + v2 * bfhi(g2.y) + v3 * bfhi(g3.y);
    }
    for (; j < end; ++j) {
        u64 e = nt_load_u64(ep + j);
        uint2 g = ((const uint2*)(src + (size_t)(u32)e * 32))[q];
        float v = __uint_as_float((u32)(e >> 32));
        acc.x += v * bflo(g.x);
        acc.y += v * bfhi(g.x);
        acc.z += v * bflo(g.y);
        acc.w += v * bfhi(g.y);
    }

    // norm reduce across the 16 lanes of this sub (xor masks < 16 stay in-sub)
    float ss = acc.x * acc.x + acc.y * acc.y + acc.z * acc.z + acc.w * acc.w;
    ss += __shfl_xor(ss, 1, 64);
    ss += __shfl_xor(ss, 2, 64);
    ss += __shfl_xor(ss, 4, 64);
    ss += __shfl_xor(ss, 8, 64);
    float inv = 1.0f / fmaxf(sqrtf(ss), 1e-12f);

    u64 o = (u64)pack_bf16x2(acc.x * inv, acc.y * inv)
          | ((u64)pack_bf16x2(acc.z * inv, acc.w * inv) << 32);
    __builtin_nontemporal_store(o, (u64*)(nxt + (size_t)row * 32) + q);
}

// Final pull: layer-3 propagation fused with the 4-layer mean.
// out[row] = (e0_fp32 + e1 + e2 + normalize(gather)) * 0.25
__global__ void lg_pull_final(const int* __restrict__ offs, const int2* __restrict__ edges,
                              const u32* __restrict__ src,      // e2 table (gather source)
                              const float4* __restrict__ user, const float4* __restrict__ item,
                              int nU,
                              const u32* __restrict__ e1b,
                              float4* __restrict__ out, int n) {
    int row = blockIdx.x * 16 + (threadIdx.x >> 4);
    if (row >= n) return;
    int q = threadIdx.x & 15;
    const u64* ep = (const u64*)edges;

    int beg = offs[row];
    int end = offs[row + 1];
    float4 acc = make_float4(0.f, 0.f, 0.f, 0.f);

    int j = beg;
    for (; j + 8 <= end; j += 8) {
        u64 e0 = nt_load_u64(ep + j + 0);
        u64 e1 = nt_load_u64(ep + j + 1);
        u64 e2 = nt_load_u64(ep + j + 2);
        u64 e3 = nt_load_u64(ep + j + 3);
        u64 e4 = nt_load_u64(ep + j + 4);
        u64 e5 = nt_load_u64(ep + j + 5);
        u64 e6 = nt_load_u64(ep + j + 6);
        u64 e7 = nt_load_u64(ep + j + 7);
        uint2 g0 = ((const uint2*)(src + (size_t)(u32)e0 * 32))[q];
        uint2 g1 = ((const uint2*)(src + (size_t)(u32)e1 * 32))[q];
        uint2 g2 = ((const uint2*)(src + (size_t)(u32)e2 * 32))[q];
        uint2 g3 = ((const uint2*)(src + (size_t)(u32)e3 * 32))[q];
        uint2 g4 = ((const uint2*)(src + (size_t)(u32)e4 * 32))[q];
        uint2 g5 = ((const uint2*)(src + (size_t)(u32)e5 * 32))[q];
        uint2 g6 = ((const uint2*)(src + (size_t)(u32)e6 * 32))[q];
        uint2 g7 = ((const uint2*)(src + (size_t)(u32)e7 * 32))[q];
        float v0 = __uint_as_float((u32)(e0 >> 32));
        float v1 = __uint_as_float((u32)(e1 >> 32));
        float v2 = __uint_as_float((u32)(e2 >> 32));
        float v3 = __uint_as_float((u32)(e3 >> 32));
        float v4 = __uint_as_float((u32)(e4 >> 32));
        float v5 = __uint_as_float((u32)(e5 >> 32));
        float v6 = __uint_as_float((u32)(e6 >> 32));
        float v7 = __uint_as_float((u32)(e7 >> 32));
        acc.x += v0 * bflo(g0.x) + v1 * bflo(g1.x) + v2 * bflo(g2.x) + v3 * bflo(g3.x)
               + v4 * bflo(g4.x) + v5 * bflo(g5.x) + v6 * bflo(g6.x) + v7 * bflo(g7.x);
        acc.y += v0 * bfhi(g0.x) + v1 * bfhi(g1.x) + v2 * bfhi(g2.x) + v3 * bfhi(g3.x)
               + v4 * bfhi(g4.x) + v5 * bfhi(g5.x) + v6 * bfhi(g6.x) + v7 * bfhi(g7.x);
        acc.z += v0 * bflo(g0.y) + v1 * bflo(g1.y) + v2 * bflo(g2.y) + v3 * bflo(g3.y)
               + v4 * bflo(g4.y) + v5 * bflo(g5.y) + v6 * bflo(g6.y) + v7 * bflo(g7.y);
        acc.w += v0 * bfhi(g0.y) + v1 * bfhi(g1.y) + v2 * bfhi(g2.y) + v3 * bfhi(g3.y)
               + v4 * bfhi(g4.y) + v5 * bfhi(g5.y) + v6 * bfhi(g6.y) + v7 * bfhi(g7.y);
    }
    for (; j + 4 <= end; j += 4) {
        u64 e0 = nt_load_u64(ep + j + 0);
        u64 e1 = nt_load_u64(ep + j + 1);
        u64 e2 = nt_load_u64(ep + j + 2);
        u64 e3 = nt_load_u64(ep + j + 3);
        uint2 g0 = ((const uint2*)(src + (size_t)(u32)e0 * 32))[q];
        uint2 g1 = ((const uint2*)(src + (size_t)(u32)e1 * 32))[q];
        uint2 g2 = ((const uint2*)(src + (size_t)(u32)e2 * 32))[q];
        uint2 g3 = ((const uint2*)(src + (size_t)(u32)e3 * 32))[q];
        float v0 = __uint_as_float((u32)(e0 >> 32));
        float v1 = __uint_as_float((u32)(e1 >> 32));
        float v2 = __uint_as_float((u32)(e2 >> 32));
        float v3 = __uint_as_float((u32)(e3 >> 32));
        acc.x += v0 * bflo(g0.x) + v1 * bflo(g1.x) + v2 * bflo(g2.x) + v3 * bflo(g3.x);
        acc.y += v0 * bfhi(g0.x) + v1 * bfhi(g1.x) + v2 * bfhi(g2.x) + v3 * bfhi(g3.x);
        acc.z += v0 * bflo(g0.y) + v1 * bflo(g1.y) + v2 * bflo(g2.y) + v3 * bflo(g3.y);
        acc.w += v0 * bfhi(g0.y) + v1 * bfhi(g1.y) + v2 * bfhi(g2.y) + v3 * bfhi(g3.y);
    }
    for (; j < end; ++j) {
        u64 e = nt_load_u64(ep + j);
        uint2 g = ((const uint2*)(src + (size_t)(u32)e * 32))[q];
        float v = __uint_as_float((u32)(e >> 32));
        acc.x += v * bflo(g.x);
        acc.y += v * bfhi(g.x);
        acc.z += v * bflo(g.y);
        acc.w += v * bfhi(g.y);
    }

    float ss = acc.x * acc.x + acc.y * acc.y + acc.z * acc.z + acc.w * acc.w;
    ss += __shfl_xor(ss, 1, 64);
    ss += __shfl_xor(ss, 2, 64);
    ss += __shfl_xor(ss, 4, 64);
    ss += __shfl_xor(ss, 8, 64);
    float inv = 1.0f / fmaxf(sqrtf(ss), 1e-12f);

    float4 a = (row < nU) ? user[(size_t)row * 16 + q] : item[(size_t)(row - nU) * 16 + q];
    uint2 b1 = ((const uint2*)(e1b + (size_t)row * 32))[q];
    uint2 b2 = ((const uint2*)(src + (size_t)row * 32))[q];
    float4 r;
    r.x = (a.x + bflo(b1.x) + bflo(b2.x) + acc.x * inv) * 0.25f;
    r.y = (a.y + bfhi(b1.x) + bfhi(b2.x) + acc.y * inv) * 0.25f;
    r.z = (a.z + bflo(b1.y) + bflo(b2.y) + acc.z * inv) * 0.25f;
    r.w = (a.w + bfhi(b1.y) + bfhi(b2.y) + acc.w * inv) * 0.25f;
    out[(size_t)row * 16 + q] = r;
}

// ---------------- fallback (atomic-scatter fp32 path) ----------------

__global__ void lg_init(const float4* __restrict__ user, const float4* __restrict__ item,
                        float4* __restrict__ cur, float4* __restrict__ sum,
                        int user_vec4, int total_vec4) {
    int i = blockIdx.x * blockDim.x + threadIdx.x;
    if (i >= total_vec4) return;
    float4 v = (i < user_vec4) ? user[i] : item[i - user_vec4];
    cur[i] = v;
    sum[i] = v;
}

__global__ void lg_scatter(const int* __restrict__ rows, const int* __restrict__ cols,
                           const float* __restrict__ vals,
                           const float* __restrict__ cur, float* __restrict__ next,
                           int nnz) {
    int gid = blockIdx.x * blockDim.x + threadIdx.x;
    int e = gid >> 6;
    int d = gid & 63;
    if (e >= nnz) return;
    atomicAdd(&next[rows[e] * D + d], vals[e] * cur[cols[e] * D + d]);
}

__global__ void lg_norm_acc(float* __restrict__ emb, float* __restrict__ sum, int n) {
    int row = blockIdx.x * (blockDim.x >> 6) + (threadIdx.x >> 6);
    int d = threadIdx.x & 63;
    if (row >= n) return;
    int idx = row * D + d;
    float v = emb[idx];
    float ss = v * v;
    #pragma unroll
    for (int off = 32; off > 0; off >>= 1) ss += __shfl_xor(ss, off, 64);
    float out = v / fmaxf(sqrtf(ss), 1e-12f);
    emb[idx] = out;
    sum[idx] += out;
}

__global__ void lg_final(float4* __restrict__ out, int n4) {
    int i = blockIdx.x * blockDim.x + threadIdx.x;
    if (i >= n4) return;
    float4 s = out[i];
    out[i] = make_float4(s.x * 0.25f, s.y * 0.25f, s.z * 0.25f, s.w * 0.25f);
}

// ---------------- launch ----------------

extern "C" void kernel_launch(void* const* d_in, const int* in_sizes, int n_in,
                              void* d_out, int out_size, void* d_ws, size_t ws_size,
                              hipStream_t stream) {
    const float* user = (const float*)d_in[0];
    const float* item = (const float*)d_in[1];
    const float* vals = (const float*)d_in[2];
    const int*   rows = (const int*)d_in[3];
    const int*   cols = (const int*)d_in[4];

    const int nU  = in_sizes[0] / D;
    const int nI  = in_sizes[1] / D;
    const int N   = nU + nI;
    const int nnz = in_sizes[2];

    const size_t embElems = (size_t)N * D;
    const size_t embU32   = (size_t)N * 32;
    const int total4 = (int)(embElems / 4);
    float* out = (float*)d_out;

    const int nbuck = (N + ROWS_PER_BUCKET - 1) / ROWS_PER_BUCKET;
    // slab capacity: avg + 1024 (~11 sigma for uniform rows), 64-aligned
    int cap = (nnz + nbuck - 1) / nbuck + 1024;
    cap = (cap + 63) & ~63;

    // ws layout
    char* p = (char*)d_ws;
    u32* t0  = (u32*)p;           p = align16(p + embU32 * sizeof(u32));
    u32* e1b = (u32*)p;           p = align16(p + embU32 * sizeof(u32));
    u32* e2b = (u32*)p;           p = align16(p + embU32 * sizeof(u32));
    int* counts   = (int*)p;      p = align16(p + (size_t)N * sizeof(int));     // fallback only
    int* offsets  = (int*)p;      p = align16(p + (size_t)(N + 1) * sizeof(int));
    int* cursor   = (int*)p;      p = align16(p + (size_t)N * sizeof(int));     // fallback only
    int* bucketOffs = (int*)p;    p = align16(p + (NBUCK_MAX + 1) * sizeof(int));
    int* bucketCursor = (int*)p;  p = align16(p + NBUCK_MAX * sizeof(int));
    u64* edges    = (u64*)p;      p = align16(p + (size_t)nnz * sizeof(u64));
    size_t needNoTmp = (size_t)(p - (char*)d_ws);
    u64* tmp      = (u64*)p;      p = align16(p + (size_t)nbuck * (size_t)cap * sizeof(u64));
    size_t needBytes = (size_t)(p - (char*)d_ws);

    if (ws_size >= needNoTmp) {
        lg_to_bf16<<<(total4 + 255) / 256, 256, 0, stream>>>(
            (const float4*)user, (const float4*)item, (uint2*)t0, nU * D / 4, total4);

        if (nbuck <= NBUCK_MAX && ws_size >= needBytes) {
            hipMemsetAsync(bucketCursor, 0, (size_t)nbuck * sizeof(int), stream);
            int ab = (nnz + BINA_CHUNK - 1) / BINA_CHUNK;
            lg_binA<<<ab, BINA_THREADS, 0, stream>>>(rows, cols, vals, bucketCursor,
                                                     tmp, nnz, nbuck, cap);
            lg_cscan<<<1, 1024, 0, stream>>>(bucketCursor, bucketOffs,
                                             offsets + N, nbuck, cap);
            lg_binB2<<<nbuck, 512, 0, stream>>>(bucketCursor, bucketOffs, tmp,
                                                offsets, (int2*)edges, N, cap);
        } else {
            hipMemsetAsync(counts, 0, (size_t)N * sizeof(int), stream);
            int eb = (nnz + 255) / 256;
            lg_hist<<<eb, 256, 0, stream>>>(rows, counts, nnz);
            lg_scan1<<<1, 1024, 0, stream>>>(counts, offsets, cursor, N);
            lg_fill<<<eb, 256, 0, stream>>>(rows, cols, vals, cursor, edges, nnz);
        }

        // ---- layers 1,2 bf16; layer 3 fused with mean ----
        int rb = (N + 15) / 16;
        lg_pull_bf16<<<rb, 256, 0, stream>>>(offsets, (const int2*)edges, t0,  e1b, N);
        lg_pull_bf16<<<rb, 256, 0, stream>>>(offsets, (const int2*)edges, e1b, e2b, N);
        lg_pull_final<<<rb, 256, 0, stream>>>(offsets, (const int2*)edges, e2b,
                                              (const float4*)user, (const float4*)item, nU,
                                              e1b, (float4*)out, N);
    } else {
        // fallback: fp32 atomic scatter
        float* buf0 = (float*)t0;
        float* buf1 = buf0 + embElems;
        float* sum  = out;
        lg_init<<<(total4 + 255) / 256, 256, 0, stream>>>(
            (const float4*)user, (const float4*)item,
            (float4*)buf0, (float4*)sum, nU * D / 4, total4);
        float* cur = buf0;
        float* nxt = buf1;
        for (int layer = 0; layer < 3; ++layer) {
            hipMemsetAsync(nxt, 0, embElems * sizeof(float), stream);
            int totThreads = nnz * 64;
            int blocks = (totThreads + 255) / 256;
            lg_scatter<<<blocks, 256, 0, stream>>>(rows, cols, vals, cur, nxt, nnz);
            lg_norm_acc<<<(N + 3) / 4, 256, 0, stream>>>(nxt, sum, N);
            float* t = cur; cur = nxt; nxt = t;
        }
        lg_final<<<(total4 + 255) / 256, 256, 0, stream>>>((float4*)sum, total4);
    }
}

// Round 9
// 365.884 us; speedup vs baseline: 1.0566x; 1.0566x over previous
//
#include <hip/hip_runtime.h>

#define D 64
// BUCKET_SHIFT 9 (512 rows/bucket): binA run length = chunk/nbuck ~28 edges,
// low partial-line write amp -- the measured binA bottleneck (R11: shorter
// runs raised WRITE_SIZE 51.7->64.4MB and dur 64.9->71us despite 2x
// occupancy; VALUBusy stayed 1.5%. Time tracks run length, not occupancy).
#define BUCKET_SHIFT 9
#define ROWS_PER_BUCKET 512
#define NBUCK_MAX 1024
#define BINA_CHUNK 8192
#define BINA_THREADS 512
// key packing in tmp: [lr:13][col:19] in low u32 (lr<=511, col<2^19 since
// NBUCK_MAX*512 = 2^19 bounds N on this path), val f32 in high u32.
#define COL_BITS 19
#define COL_MASK ((1u << COL_BITS) - 1u)

typedef unsigned int u32;
typedef unsigned long long u64;

static inline char* align16(char* p) {
    return (char*)(((uintptr_t)p + 15) & ~(uintptr_t)15);
}

// bf16x2 helpers (packed pair in one u32; low ushort = even element)
__device__ __forceinline__ float bflo(u32 p) { return __uint_as_float(p << 16); }
__device__ __forceinline__ float bfhi(u32 p) { return __uint_as_float(p & 0xFFFF0000u); }
__device__ __forceinline__ u32 pack_bf16x2(float a, float b) {
    u32 ua = __float_as_uint(a);
    u32 ub = __float_as_uint(b);
    ua = (ua + 0x7FFFu + ((ua >> 16) & 1u)) >> 16;   // RNE
    ub = (ub + 0x7FFFu + ((ub >> 16) & 1u)) >> 16;
    return ua | (ub << 16);
}

// ---------------- init ----------------

__global__ void lg_to_bf16(const float4* __restrict__ user, const float4* __restrict__ item,
                           uint2* __restrict__ dst, int user_vec4, int total_vec4) {
    int i = blockIdx.x * blockDim.x + threadIdx.x;
    if (i >= total_vec4) return;
    float4 v = (i < user_vec4) ? user[i] : item[i - user_vec4];
    dst[i] = make_uint2(pack_bf16x2(v.x, v.y), pack_bf16x2(v.z, v.w));
}

// ---------------- two-level bucket sort ----------------
// R13: no global pre-histogram/pre-scan. Each bucket gets a fixed-capacity
// slab in tmp (cap = avg + 1024 ~ 11 sigma for uniform-random rows); binA
// reserves runs with b*cap + atomicAdd directly. lg_cscan (1 tiny block)
// then scans the resulting counts into CSR bucket bases for binB2.

// Pass A: LDS hist -> one global atomic per (block,bucket) to reserve a run
// in the bucket's slab -> direct global scatter. Chunk 8192 (293 blocks ~
// 1.14/CU): keep runs long (see BUCKET_SHIFT note).
__global__ void lg_binA(const int* __restrict__ rows, const int* __restrict__ cols,
                        const float* __restrict__ vals, int* __restrict__ bucketCursor,
                        u64* __restrict__ tmp, int nnz, int nbuck, int cap) {
    __shared__ int hist[NBUCK_MAX];
    __shared__ int base[NBUCK_MAX];
    int tid = threadIdx.x;
    int bstart = blockIdx.x * BINA_CHUNK;
    int bend = min(bstart + BINA_CHUNK, nnz);

    for (int i = tid; i < nbuck; i += BINA_THREADS) hist[i] = 0;
    __syncthreads();
    for (int e = bstart + tid; e < bend; e += BINA_THREADS)
        atomicAdd(&hist[rows[e] >> BUCKET_SHIFT], 1);
    __syncthreads();
    for (int b = tid; b < nbuck; b += BINA_THREADS) {
        int c = hist[b];
        base[b] = (c > 0) ? (b * cap + atomicAdd(&bucketCursor[b], c)) : 0;
        hist[b] = 0;   // reuse as local cursor
    }
    __syncthreads();
    for (int e = bstart + tid; e < bend; e += BINA_THREADS) {
        int r = rows[e];
        int b = r >> BUCKET_SHIFT;
        int pos = base[b] + atomicAdd(&hist[b], 1);
        // overflow tripwire: never taken for uniform-random rows (11 sigma);
        // guards memory safety -- an overflow drops edges => loud absmax fail.
        if (pos < (b + 1) * cap) {
            u32 key = ((u32)(r & (ROWS_PER_BUCKET - 1)) << COL_BITS) | (u32)cols[e];
            u64 packed = (u64)key | ((u64)__float_as_uint(vals[e]) << 32);
            tmp[pos] = packed;
        }
    }
}

// Tiny scan over per-bucket counts -> CSR bucket bases. 1 block.
__global__ void lg_cscan(const int* __restrict__ bucketCursor, int* __restrict__ bucketOffs,
                         int* __restrict__ offsets_end, int nbuck, int cap) {
    __shared__ int s[1024];
    int t = threadIdx.x;
    int v = (t < nbuck) ? min(bucketCursor[t], cap) : 0;
    s[t] = v;
    __syncthreads();
    #pragma unroll
    for (int off = 1; off < 1024; off <<= 1) {
        int x = (t >= off) ? s[t - off] : 0;
        __syncthreads();
        s[t] += x;
        __syncthreads();
    }
    if (t < nbuck) bucketOffs[t] = s[t] - v;
    if (t == 1023) {
        bucketOffs[nbuck] = s[1023];
        *offsets_end = s[1023];
    }
}

// Pass B2: one block per bucket (512 rows); per-row hist+scan in LDS ->
// emits final per-row CSR offsets and scatters edges into CSR order
// (L2-local 64KB window, single-writer lines -> low write amp).
__global__ void lg_binB2(const int* __restrict__ bucketCursor, const int* __restrict__ bucketOffs,
                         const u64* __restrict__ tmp,
                         int* __restrict__ offsets, int2* __restrict__ edges, int n, int cap) {
    __shared__ int h[ROWS_PER_BUCKET];
    __shared__ int s[ROWS_PER_BUCKET];
    __shared__ int cur[ROWS_PER_BUCKET];
    int bucket = blockIdx.x;
    int row0 = bucket << BUCKET_SHIFT;
    int tid = threadIdx.x;
    size_t tbase = (size_t)bucket * (size_t)cap;
    int cnt = min(bucketCursor[bucket], cap);
    int cbase = bucketOffs[bucket];

    h[tid] = 0;
    __syncthreads();
    for (int e = tid; e < cnt; e += 512)
        atomicAdd(&h[(u32)((u32)tmp[tbase + e]) >> COL_BITS], 1);
    __syncthreads();
    int v = h[tid];
    s[tid] = v;
    __syncthreads();
    #pragma unroll
    for (int off = 1; off < 512; off <<= 1) {
        int x = (tid >= off) ? s[tid - off] : 0;
        __syncthreads();
        s[tid] += x;
        __syncthreads();
    }
    int rowOff = cbase + s[tid] - v;
    int r = row0 + tid;
    if (r < n) offsets[r] = rowOff;
    cur[tid] = rowOff;
    __syncthreads();
    for (int e = tid; e < cnt; e += 512) {
        u64 p = tmp[tbase + e];
        u32 key = (u32)p;
        int lr = key >> COL_BITS;
        int col = (int)(key & COL_MASK);
        int pos = atomicAdd(&cur[lr], 1);
        edges[pos] = make_int2(col, (int)(u32)(p >> 32));
    }
}

// ---------------- fallback CSR build ----------------

__global__ void lg_hist(const int* __restrict__ rows, int* __restrict__ counts, int nnz) {
    int e = blockIdx.x * blockDim.x + threadIdx.x;
    if (e >= nnz) return;
    atomicAdd(&counts[rows[e]], 1);
}

__global__ void lg_scan1(const int* __restrict__ counts, int* __restrict__ offsets,
                         int* __restrict__ cursor, int n) {
    const int T = 1024;
    int t = threadIdx.x;
    int chunk = (n + T - 1) / T;
    int start = t * chunk;
    int end = min(start + chunk, n);
    int sum = 0;
    for (int i = start; i < end; ++i) sum += counts[i];
    __shared__ int sdata[T];
    sdata[t] = sum;
    __syncthreads();
    #pragma unroll
    for (int off = 1; off < T; off <<= 1) {
        int v = (t >= off) ? sdata[t - off] : 0;
        __syncthreads();
        sdata[t] += v;
        __syncthreads();
    }
    int offset = sdata[t] - sum;
    for (int i = start; i < end; ++i) {
        int c = counts[i];
        offsets[i] = offset;
        cursor[i] = offset;
        offset += c;
    }
    if (t == T - 1) offsets[n] = sdata[T - 1];
}

__global__ void lg_fill(const int* __restrict__ rows, const int* __restrict__ cols,
                        const float* __restrict__ vals, int* __restrict__ cursor,
                        u64* __restrict__ edges, int nnz) {
    int e = blockIdx.x * blockDim.x + threadIdx.x;
    if (e >= nnz) return;
    int pos = atomicAdd(&cursor[rows[e]], 1);
    u64 packed = (u64)(u32)cols[e] | ((u64)__float_as_uint(vals[e]) << 32);
    edges[pos] = packed;
}

// ---------------- pull SpMM (bf16 gather, fp32 accumulate) ----------------
// R10: one 16-lane sub-group owns one full row (lane q = dims 4q..4q+3).
// R16: unroll-16 first tier (73% of edges), then proven 8/4/1 tails. The
// pulls scale with per-wave gather MLP (2.6->3.66 TB/s from R0->R12), i.e.
// MSHR/latency-limited. R14 (predication) and R15 (NT hints) both FAILED --
// keep plain loads, compile-time indices, no hints.

__global__ void lg_pull_bf16(const int* __restrict__ offs, const int2* __restrict__ edges,
                             const u32* __restrict__ src,
                             u32* __restrict__ nxt, int n) {
    int row = blockIdx.x * 16 + (threadIdx.x >> 4);
    if (row >= n) return;
    int q = threadIdx.x & 15;

    int beg = offs[row];
    int end = offs[row + 1];
    float4 acc = make_float4(0.f, 0.f, 0.f, 0.f);

    int j = beg;
    for (; j + 16 <= end; j += 16) {
        int2 e[16];
        #pragma unroll
        for (int k = 0; k < 16; ++k) e[k] = edges[j + k];
        uint2 g[16];
        #pragma unroll
        for (int k = 0; k < 16; ++k)
            g[k] = ((const uint2*)(src + (size_t)e[k].x * 32))[q];
        #pragma unroll
        for (int k = 0; k < 16; ++k) {
            float v = __int_as_float(e[k].y);
            acc.x += v * bflo(g[k].x);
            acc.y += v * bfhi(g[k].x);
            acc.z += v * bflo(g[k].y);
            acc.w += v * bfhi(g[k].y);
        }
    }
    for (; j + 8 <= end; j += 8) {
        int2 e[8];
        #pragma unroll
        for (int k = 0; k < 8; ++k) e[k] = edges[j + k];
        uint2 g[8];
        #pragma unroll
        for (int k = 0; k < 8; ++k)
            g[k] = ((const uint2*)(src + (size_t)e[k].x * 32))[q];
        #pragma unroll
        for (int k = 0; k < 8; ++k) {
            float v = __int_as_float(e[k].y);
            acc.x += v * bflo(g[k].x);
            acc.y += v * bfhi(g[k].x);
            acc.z += v * bflo(g[k].y);
            acc.w += v * bfhi(g[k].y);
        }
    }
    for (; j + 4 <= end; j += 4) {
        int2 e0 = edges[j + 0];
        int2 e1 = edges[j + 1];
        int2 e2 = edges[j + 2];
        int2 e3 = edges[j + 3];
        uint2 g0 = ((const uint2*)(src + (size_t)e0.x * 32))[q];
        uint2 g1 = ((const uint2*)(src + (size_t)e1.x * 32))[q];
        uint2 g2 = ((const uint2*)(src + (size_t)e2.x * 32))[q];
        uint2 g3 = ((const uint2*)(src + (size_t)e3.x * 32))[q];
        float v0 = __int_as_float(e0.y);
        float v1 = __int_as_float(e1.y);
        float v2 = __int_as_float(e2.y);
        float v3 = __int_as_float(e3.y);
        acc.x += v0 * bflo(g0.x) + v1 * bflo(g1.x) + v2 * bflo(g2.x) + v3 * bflo(g3.x);
        acc.y += v0 * bfhi(g0.x) + v1 * bfhi(g1.x) + v2 * bfhi(g2.x) + v3 * bfhi(g3.x);
        acc.z += v0 * bflo(g0.y) + v1 * bflo(g1.y) + v2 * bflo(g2.y) + v3 * bflo(g3.y);
        acc.w += v0 * bfhi(g0.y) + v1 * bfhi(g1.y) + v2 * bfhi(g2.y) + v3 * bfhi(g3.y);
    }
    for (; j < end; ++j) {
        int2 e = edges[j];
        uint2 g = ((const uint2*)(src + (size_t)e.x * 32))[q];
        float v = __int_as_float(e.y);
        acc.x += v * bflo(g.x);
        acc.y += v * bfhi(g.x);
        acc.z += v * bflo(g.y);
        acc.w += v * bfhi(g.y);
    }

    // norm reduce across the 16 lanes of this sub (xor masks < 16 stay in-sub)
    float ss = acc.x * acc.x + acc.y * acc.y + acc.z * acc.z + acc.w * acc.w;
    ss += __shfl_xor(ss, 1, 64);
    ss += __shfl_xor(ss, 2, 64);
    ss += __shfl_xor(ss, 4, 64);
    ss += __shfl_xor(ss, 8, 64);
    float inv = 1.0f / fmaxf(sqrtf(ss), 1e-12f);

    uint2 o = make_uint2(pack_bf16x2(acc.x * inv, acc.y * inv),
                         pack_bf16x2(acc.z * inv, acc.w * inv));
    ((uint2*)(nxt + (size_t)row * 32))[q] = o;
}

// Final pull: layer-3 propagation fused with the 4-layer mean.
// out[row] = (e0_fp32 + e1 + e2 + normalize(gather)) * 0.25
__global__ void lg_pull_final(const int* __restrict__ offs, const int2* __restrict__ edges,
                              const u32* __restrict__ src,      // e2 table (gather source)
                              const float4* __restrict__ user, const float4* __restrict__ item,
                              int nU,
                              const u32* __restrict__ e1b,
                              float4* __restrict__ out, int n) {
    int row = blockIdx.x * 16 + (threadIdx.x >> 4);
    if (row >= n) return;
    int q = threadIdx.x & 15;

    int beg = offs[row];
    int end = offs[row + 1];
    float4 acc = make_float4(0.f, 0.f, 0.f, 0.f);

    int j = beg;
    for (; j + 16 <= end; j += 16) {
        int2 e[16];
        #pragma unroll
        for (int k = 0; k < 16; ++k) e[k] = edges[j + k];
        uint2 g[16];
        #pragma unroll
        for (int k = 0; k < 16; ++k)
            g[k] = ((const uint2*)(src + (size_t)e[k].x * 32))[q];
        #pragma unroll
        for (int k = 0; k < 16; ++k) {
            float v = __int_as_float(e[k].y);
            acc.x += v * bflo(g[k].x);
            acc.y += v * bfhi(g[k].x);
            acc.z += v * bflo(g[k].y);
            acc.w += v * bfhi(g[k].y);
        }
    }
    for (; j + 8 <= end; j += 8) {
        int2 e[8];
        #pragma unroll
        for (int k = 0; k < 8; ++k) e[k] = edges[j + k];
        uint2 g[8];
        #pragma unroll
        for (int k = 0; k < 8; ++k)
            g[k] = ((const uint2*)(src + (size_t)e[k].x * 32))[q];
        #pragma unroll
        for (int k = 0; k < 8; ++k) {
            float v = __int_as_float(e[k].y);
            acc.x += v * bflo(g[k].x);
            acc.y += v * bfhi(g[k].x);
            acc.z += v * bflo(g[k].y);
            acc.w += v * bfhi(g[k].y);
        }
    }
    for (; j + 4 <= end; j += 4) {
        int2 e0 = edges[j + 0];
        int2 e1 = edges[j + 1];
        int2 e2 = edges[j + 2];
        int2 e3 = edges[j + 3];
        uint2 g0 = ((const uint2*)(src + (size_t)e0.x * 32))[q];
        uint2 g1 = ((const uint2*)(src + (size_t)e1.x * 32))[q];
        uint2 g2 = ((const uint2*)(src + (size_t)e2.x * 32))[q];
        uint2 g3 = ((const uint2*)(src + (size_t)e3.x * 32))[q];
        float v0 = __int_as_float(e0.y);
        float v1 = __int_as_float(e1.y);
        float v2 = __int_as_float(e2.y);
        float v3 = __int_as_float(e3.y);
        acc.x += v0 * bflo(g0.x) + v1 * bflo(g1.x) + v2 * bflo(g2.x) + v3 * bflo(g3.x);
        acc.y += v0 * bfhi(g0.x) + v1 * bfhi(g1.x) + v2 * bfhi(g2.x) + v3 * bfhi(g3.x);
        acc.z += v0 * bflo(g0.y) + v1 * bflo(g1.y) + v2 * bflo(g2.y) + v3 * bflo(g3.y);
        acc.w += v0 * bfhi(g0.y) + v1 * bfhi(g1.y) + v2 * bfhi(g2.y) + v3 * bfhi(g3.y);
    }
    for (; j < end; ++j) {
        int2 e = edges[j];
        uint2 g = ((const uint2*)(src + (size_t)e.x * 32))[q];
        float v = __int_as_float(e.y);
        acc.x += v * bflo(g.x);
        acc.y += v * bfhi(g.x);
        acc.z += v * bflo(g.y);
        acc.w += v * bfhi(g.y);
    }

    float ss = acc.x * acc.x + acc.y * acc.y + acc.z * acc.z + acc.w * acc.w;
    ss += __shfl_xor(ss, 1, 64);
    ss += __shfl_xor(ss, 2, 64);
    ss += __shfl_xor(ss, 4, 64);
    ss += __shfl_xor(ss, 8, 64);
    float inv = 1.0f / fmaxf(sqrtf(ss), 1e-12f);

    float4 a = (row < nU) ? user[(size_t)row * 16 + q] : item[(size_t)(row - nU) * 16 + q];
    uint2 b1 = ((const uint2*)(e1b + (size_t)row * 32))[q];
    uint2 b2 = ((const uint2*)(src + (size_t)row * 32))[q];
    float4 r;
    r.x = (a.x + bflo(b1.x) + bflo(b2.x) + acc.x * inv) * 0.25f;
    r.y = (a.y + bfhi(b1.x) + bfhi(b2.x) + acc.y * inv) * 0.25f;
    r.z = (a.z + bflo(b1.y) + bflo(b2.y) + acc.z * inv) * 0.25f;
    r.w = (a.w + bfhi(b1.y) + bfhi(b2.y) + acc.w * inv) * 0.25f;
    out[(size_t)row * 16 + q] = r;
}

// ---------------- fallback (atomic-scatter fp32 path) ----------------

__global__ void lg_init(const float4* __restrict__ user, const float4* __restrict__ item,
                        float4* __restrict__ cur, float4* __restrict__ sum,
                        int user_vec4, int total_vec4) {
    int i = blockIdx.x * blockDim.x + threadIdx.x;
    if (i >= total_vec4) return;
    float4 v = (i < user_vec4) ? user[i] : item[i - user_vec4];
    cur[i] = v;
    sum[i] = v;
}

__global__ void lg_scatter(const int* __restrict__ rows, const int* __restrict__ cols,
                           const float* __restrict__ vals,
                           const float* __restrict__ cur, float* __restrict__ next,
                           int nnz) {
    int gid = blockIdx.x * blockDim.x + threadIdx.x;
    int e = gid >> 6;
    int d = gid & 63;
    if (e >= nnz) return;
    atomicAdd(&next[rows[e] * D + d], vals[e] * cur[cols[e] * D + d]);
}

__global__ void lg_norm_acc(float* __restrict__ emb, float* __restrict__ sum, int n) {
    int row = blockIdx.x * (blockDim.x >> 6) + (threadIdx.x >> 6);
    int d = threadIdx.x & 63;
    if (row >= n) return;
    int idx = row * D + d;
    float v = emb[idx];
    float ss = v * v;
    #pragma unroll
    for (int off = 32; off > 0; off >>= 1) ss += __shfl_xor(ss, off, 64);
    float out = v / fmaxf(sqrtf(ss), 1e-12f);
    emb[idx] = out;
    sum[idx] += out;
}

__global__ void lg_final(float4* __restrict__ out, int n4) {
    int i = blockIdx.x * blockDim.x + threadIdx.x;
    if (i >= n4) return;
    float4 s = out[i];
    out[i] = make_float4(s.x * 0.25f, s.y * 0.25f, s.z * 0.25f, s.w * 0.25f);
}

// ---------------- launch ----------------

extern "C" void kernel_launch(void* const* d_in, const int* in_sizes, int n_in,
                              void* d_out, int out_size, void* d_ws, size_t ws_size,
                              hipStream_t stream) {
    const float* user = (const float*)d_in[0];
    const float* item = (const float*)d_in[1];
    const float* vals = (const float*)d_in[2];
    const int*   rows = (const int*)d_in[3];
    const int*   cols = (const int*)d_in[4];

    const int nU  = in_sizes[0] / D;
    const int nI  = in_sizes[1] / D;
    const int N   = nU + nI;
    const int nnz = in_sizes[2];

    const size_t embElems = (size_t)N * D;
    const size_t embU32   = (size_t)N * 32;
    const int total4 = (int)(embElems / 4);
    float* out = (float*)d_out;

    const int nbuck = (N + ROWS_PER_BUCKET - 1) / ROWS_PER_BUCKET;
    // slab capacity: avg + 1024 (~11 sigma for uniform rows), 64-aligned
    int cap = (nnz + nbuck - 1) / nbuck + 1024;
    cap = (cap + 63) & ~63;

    // ws layout
    char* p = (char*)d_ws;
    u32* t0  = (u32*)p;           p = align16(p + embU32 * sizeof(u32));
    u32* e1b = (u32*)p;           p = align16(p + embU32 * sizeof(u32));
    u32* e2b = (u32*)p;           p = align16(p + embU32 * sizeof(u32));
    int* counts   = (int*)p;      p = align16(p + (size_t)N * sizeof(int));     // fallback only
    int* offsets  = (int*)p;      p = align16(p + (size_t)(N + 1) * sizeof(int));
    int* cursor   = (int*)p;      p = align16(p + (size_t)N * sizeof(int));     // fallback only
    int* bucketOffs = (int*)p;    p = align16(p + (NBUCK_MAX + 1) * sizeof(int));
    int* bucketCursor = (int*)p;  p = align16(p + NBUCK_MAX * sizeof(int));
    u64* edges    = (u64*)p;      p = align16(p + (size_t)nnz * sizeof(u64));
    size_t needNoTmp = (size_t)(p - (char*)d_ws);
    u64* tmp      = (u64*)p;      p = align16(p + (size_t)nbuck * (size_t)cap * sizeof(u64));
    size_t needBytes = (size_t)(p - (char*)d_ws);

    if (ws_size >= needNoTmp) {
        lg_to_bf16<<<(total4 + 255) / 256, 256, 0, stream>>>(
            (const float4*)user, (const float4*)item, (uint2*)t0, nU * D / 4, total4);

        if (nbuck <= NBUCK_MAX && ws_size >= needBytes) {
            hipMemsetAsync(bucketCursor, 0, (size_t)nbuck * sizeof(int), stream);
            int ab = (nnz + BINA_CHUNK - 1) / BINA_CHUNK;
            lg_binA<<<ab, BINA_THREADS, 0, stream>>>(rows, cols, vals, bucketCursor,
                                                     tmp, nnz, nbuck, cap);
            lg_cscan<<<1, 1024, 0, stream>>>(bucketCursor, bucketOffs,
                                             offsets + N, nbuck, cap);
            lg_binB2<<<nbuck, 512, 0, stream>>>(bucketCursor, bucketOffs, tmp,
                                                offsets, (int2*)edges, N, cap);
        } else {
            hipMemsetAsync(counts, 0, (size_t)N * sizeof(int), stream);
            int eb = (nnz + 255) / 256;
            lg_hist<<<eb, 256, 0, stream>>>(rows, counts, nnz);
            lg_scan1<<<1, 1024, 0, stream>>>(counts, offsets, cursor, N);
            lg_fill<<<eb, 256, 0, stream>>>(rows, cols, vals, cursor, edges, nnz);
        }

        // ---- layers 1,2 bf16; layer 3 fused with mean ----
        int rb = (N + 15) / 16;
        lg_pull_bf16<<<rb, 256, 0, stream>>>(offsets, (const int2*)edges, t0,  e1b, N);
        lg_pull_bf16<<<rb, 256, 0, stream>>>(offsets, (const int2*)edges, e1b, e2b, N);
        lg_pull_final<<<rb, 256, 0, stream>>>(offsets, (const int2*)edges, e2b,
                                              (const float4*)user, (const float4*)item, nU,
                                              e1b, (float4*)out, N);
    } else {
        // fallback: fp32 atomic scatter
        float* buf0 = (float*)t0;
        float* buf1 = buf0 + embElems;
        float* sum  = out;
        lg_init<<<(total4 + 255) / 256, 256, 0, stream>>>(
            (const float4*)user, (const float4*)item,
            (float4*)buf0, (float4*)sum, nU * D / 4, total4);
        float* cur = buf0;
        float* nxt = buf1;
        for (int layer = 0; layer < 3; ++layer) {
            hipMemsetAsync(nxt, 0, embElems * sizeof(float), stream);
            int totThreads = nnz * 64;
            int blocks = (totThreads + 255) / 256;
            lg_scatter<<<blocks, 256, 0, stream>>>(rows, cols, vals, cur, nxt, nnz);
            lg_norm_acc<<<(N + 3) / 4, 256, 0, stream>>>(nxt, sum, N);
            float* t = cur; cur = nxt; nxt = t;
        }
        lg_final<<<(total4 + 255) / 256, 256, 0, stream>>>((float4*)sum, total4);
    }
}

// Round 10
// 351.815 us; speedup vs baseline: 1.0989x; 1.0400x over previous
//
#include <hip/hip_runtime.h>

#define D 64
// BUCKET_SHIFT 9 (512 rows/bucket): binA run length = chunk/nbuck ~28 edges,
// low partial-line write amp -- the measured binA bottleneck (R11: shorter
// runs raised WRITE_SIZE 51.7->64.4MB and dur 64.9->71us despite 2x
// occupancy; VALUBusy stayed 1.5%. Time tracks run length, not occupancy).
#define BUCKET_SHIFT 9
#define ROWS_PER_BUCKET 512
#define NBUCK_MAX 1024
#define BINA_CHUNK 8192
#define BINA_THREADS 512
// key packing in tmp: [lr:13][col:19] in low u32 (lr<=511, col<2^19 since
// NBUCK_MAX*512 = 2^19 bounds N on this path), val f32 in high u32.
#define COL_BITS 19
#define COL_MASK ((1u << COL_BITS) - 1u)

typedef unsigned int u32;
typedef unsigned long long u64;

static inline char* align16(char* p) {
    return (char*)(((uintptr_t)p + 15) & ~(uintptr_t)15);
}

// bf16x2 helpers (packed pair in one u32; low ushort = even element)
__device__ __forceinline__ float bflo(u32 p) { return __uint_as_float(p << 16); }
__device__ __forceinline__ float bfhi(u32 p) { return __uint_as_float(p & 0xFFFF0000u); }
__device__ __forceinline__ u32 pack_bf16x2(float a, float b) {
    u32 ua = __float_as_uint(a);
    u32 ub = __float_as_uint(b);
    ua = (ua + 0x7FFFu + ((ua >> 16) & 1u)) >> 16;   // RNE
    ub = (ub + 0x7FFFu + ((ub >> 16) & 1u)) >> 16;
    return ua | (ub << 16);
}

// ---------------- init ----------------

__global__ void lg_to_bf16(const float4* __restrict__ user, const float4* __restrict__ item,
                           uint2* __restrict__ dst, int user_vec4, int total_vec4) {
    int i = blockIdx.x * blockDim.x + threadIdx.x;
    if (i >= total_vec4) return;
    float4 v = (i < user_vec4) ? user[i] : item[i - user_vec4];
    dst[i] = make_uint2(pack_bf16x2(v.x, v.y), pack_bf16x2(v.z, v.w));
}

// ---------------- two-level bucket sort ----------------
// R13: no global pre-histogram/pre-scan. Each bucket gets a fixed-capacity
// slab in tmp (cap = avg + 1024 ~ 11 sigma for uniform-random rows); binA
// reserves runs with b*cap + atomicAdd directly. lg_cscan (1 tiny block)
// then scans the resulting counts into CSR bucket bases for binB2.

// Pass A: LDS hist -> one global atomic per (block,bucket) to reserve a run
// in the bucket's slab -> direct global scatter. Chunk 8192 (293 blocks ~
// 1.14/CU): keep runs long (see BUCKET_SHIFT note).
__global__ void lg_binA(const int* __restrict__ rows, const int* __restrict__ cols,
                        const float* __restrict__ vals, int* __restrict__ bucketCursor,
                        u64* __restrict__ tmp, int nnz, int nbuck, int cap) {
    __shared__ int hist[NBUCK_MAX];
    __shared__ int base[NBUCK_MAX];
    int tid = threadIdx.x;
    int bstart = blockIdx.x * BINA_CHUNK;
    int bend = min(bstart + BINA_CHUNK, nnz);

    for (int i = tid; i < nbuck; i += BINA_THREADS) hist[i] = 0;
    __syncthreads();
    for (int e = bstart + tid; e < bend; e += BINA_THREADS)
        atomicAdd(&hist[rows[e] >> BUCKET_SHIFT], 1);
    __syncthreads();
    for (int b = tid; b < nbuck; b += BINA_THREADS) {
        int c = hist[b];
        base[b] = (c > 0) ? (b * cap + atomicAdd(&bucketCursor[b], c)) : 0;
        hist[b] = 0;   // reuse as local cursor
    }
    __syncthreads();
    for (int e = bstart + tid; e < bend; e += BINA_THREADS) {
        int r = rows[e];
        int b = r >> BUCKET_SHIFT;
        int pos = base[b] + atomicAdd(&hist[b], 1);
        // overflow tripwire: never taken for uniform-random rows (11 sigma);
        // guards memory safety -- an overflow drops edges => loud absmax fail.
        if (pos < (b + 1) * cap) {
            u32 key = ((u32)(r & (ROWS_PER_BUCKET - 1)) << COL_BITS) | (u32)cols[e];
            u64 packed = (u64)key | ((u64)__float_as_uint(vals[e]) << 32);
            tmp[pos] = packed;
        }
    }
}

// Tiny scan over per-bucket counts -> CSR bucket bases. 1 block.
__global__ void lg_cscan(const int* __restrict__ bucketCursor, int* __restrict__ bucketOffs,
                         int* __restrict__ offsets_end, int nbuck, int cap) {
    __shared__ int s[1024];
    int t = threadIdx.x;
    int v = (t < nbuck) ? min(bucketCursor[t], cap) : 0;
    s[t] = v;
    __syncthreads();
    #pragma unroll
    for (int off = 1; off < 1024; off <<= 1) {
        int x = (t >= off) ? s[t - off] : 0;
        __syncthreads();
        s[t] += x;
        __syncthreads();
    }
    if (t < nbuck) bucketOffs[t] = s[t] - v;
    if (t == 1023) {
        bucketOffs[nbuck] = s[1023];
        *offsets_end = s[1023];
    }
}

// Pass B2: one block per bucket (512 rows); per-row hist+scan in LDS ->
// emits final per-row CSR offsets and scatters edges into CSR order
// (L2-local 64KB window, single-writer lines -> low write amp).
__global__ void lg_binB2(const int* __restrict__ bucketCursor, const int* __restrict__ bucketOffs,
                         const u64* __restrict__ tmp,
                         int* __restrict__ offsets, int2* __restrict__ edges, int n, int cap) {
    __shared__ int h[ROWS_PER_BUCKET];
    __shared__ int s[ROWS_PER_BUCKET];
    __shared__ int cur[ROWS_PER_BUCKET];
    int bucket = blockIdx.x;
    int row0 = bucket << BUCKET_SHIFT;
    int tid = threadIdx.x;
    size_t tbase = (size_t)bucket * (size_t)cap;
    int cnt = min(bucketCursor[bucket], cap);
    int cbase = bucketOffs[bucket];

    h[tid] = 0;
    __syncthreads();
    for (int e = tid; e < cnt; e += 512)
        atomicAdd(&h[(u32)((u32)tmp[tbase + e]) >> COL_BITS], 1);
    __syncthreads();
    int v = h[tid];
    s[tid] = v;
    __syncthreads();
    #pragma unroll
    for (int off = 1; off < 512; off <<= 1) {
        int x = (tid >= off) ? s[tid - off] : 0;
        __syncthreads();
        s[tid] += x;
        __syncthreads();
    }
    int rowOff = cbase + s[tid] - v;
    int r = row0 + tid;
    if (r < n) offsets[r] = rowOff;
    cur[tid] = rowOff;
    __syncthreads();
    for (int e = tid; e < cnt; e += 512) {
        u64 p = tmp[tbase + e];
        u32 key = (u32)p;
        int lr = key >> COL_BITS;
        int col = (int)(key & COL_MASK);
        int pos = atomicAdd(&cur[lr], 1);
        edges[pos] = make_int2(col, (int)(u32)(p >> 32));
    }
}

// ---------------- fallback CSR build ----------------

__global__ void lg_hist(const int* __restrict__ rows, int* __restrict__ counts, int nnz) {
    int e = blockIdx.x * blockDim.x + threadIdx.x;
    if (e >= nnz) return;
    atomicAdd(&counts[rows[e]], 1);
}

__global__ void lg_scan1(const int* __restrict__ counts, int* __restrict__ offsets,
                         int* __restrict__ cursor, int n) {
    const int T = 1024;
    int t = threadIdx.x;
    int chunk = (n + T - 1) / T;
    int start = t * chunk;
    int end = min(start + chunk, n);
    int sum = 0;
    for (int i = start; i < end; ++i) sum += counts[i];
    __shared__ int sdata[T];
    sdata[t] = sum;
    __syncthreads();
    #pragma unroll
    for (int off = 1; off < T; off <<= 1) {
        int v = (t >= off) ? sdata[t - off] : 0;
        __syncthreads();
        sdata[t] += v;
        __syncthreads();
    }
    int offset = sdata[t] - sum;
    for (int i = start; i < end; ++i) {
        int c = counts[i];
        offsets[i] = offset;
        cursor[i] = offset;
        offset += c;
    }
    if (t == T - 1) offsets[n] = sdata[T - 1];
}

__global__ void lg_fill(const int* __restrict__ rows, const int* __restrict__ cols,
                        const float* __restrict__ vals, int* __restrict__ cursor,
                        u64* __restrict__ edges, int nnz) {
    int e = blockIdx.x * blockDim.x + threadIdx.x;
    if (e >= nnz) return;
    int pos = atomicAdd(&cursor[rows[e]], 1);
    u64 packed = (u64)(u32)cols[e] | ((u64)__float_as_uint(vals[e]) << 32);
    edges[pos] = packed;
}

// ---------------- pull SpMM (bf16 gather, fp32 accumulate) ----------------
// R17: 8-lane sub owns one row, lane q loads 16B (uint4 = dims 8q..8q+7).
// One gather instruction now covers 8 edges (vs 4 at 16-lane/uint2) at
// 1KB/instr: halves gather instruction count, doubles edges in flight per
// wave, same proven 8-deep load clause (g[8]=32 VGPR -- the budget the
// compiler actually grants; R16's unroll-16 was split by regalloc, VGPR=36).
// R14 (predication) / R15 (NT hints) / R16 (unroll-16) all FAILED -- keep
// plain loads, 8/4/1 tails.

__global__ void lg_pull_bf16(const int* __restrict__ offs, const int2* __restrict__ edges,
                             const u32* __restrict__ src,
                             u32* __restrict__ nxt, int n) {
    int row = blockIdx.x * 32 + (threadIdx.x >> 3);
    if (row >= n) return;
    int q = threadIdx.x & 7;

    int beg = offs[row];
    int end = offs[row + 1];
    float4 acc0 = make_float4(0.f, 0.f, 0.f, 0.f);
    float4 acc1 = make_float4(0.f, 0.f, 0.f, 0.f);

    int j = beg;
    for (; j + 8 <= end; j += 8) {
        int2 e[8];
        #pragma unroll
        for (int k = 0; k < 8; ++k) e[k] = edges[j + k];
        uint4 g[8];
        #pragma unroll
        for (int k = 0; k < 8; ++k)
            g[k] = ((const uint4*)(src + (size_t)e[k].x * 32))[q];
        #pragma unroll
        for (int k = 0; k < 8; ++k) {
            float v = __int_as_float(e[k].y);
            acc0.x += v * bflo(g[k].x);
            acc0.y += v * bfhi(g[k].x);
            acc0.z += v * bflo(g[k].y);
            acc0.w += v * bfhi(g[k].y);
            acc1.x += v * bflo(g[k].z);
            acc1.y += v * bfhi(g[k].z);
            acc1.z += v * bflo(g[k].w);
            acc1.w += v * bfhi(g[k].w);
        }
    }
    for (; j + 4 <= end; j += 4) {
        int2 e[4];
        #pragma unroll
        for (int k = 0; k < 4; ++k) e[k] = edges[j + k];
        uint4 g[4];
        #pragma unroll
        for (int k = 0; k < 4; ++k)
            g[k] = ((const uint4*)(src + (size_t)e[k].x * 32))[q];
        #pragma unroll
        for (int k = 0; k < 4; ++k) {
            float v = __int_as_float(e[k].y);
            acc0.x += v * bflo(g[k].x);
            acc0.y += v * bfhi(g[k].x);
            acc0.z += v * bflo(g[k].y);
            acc0.w += v * bfhi(g[k].y);
            acc1.x += v * bflo(g[k].z);
            acc1.y += v * bfhi(g[k].z);
            acc1.z += v * bflo(g[k].w);
            acc1.w += v * bfhi(g[k].w);
        }
    }
    for (; j < end; ++j) {
        int2 e = edges[j];
        uint4 g = ((const uint4*)(src + (size_t)e.x * 32))[q];
        float v = __int_as_float(e.y);
        acc0.x += v * bflo(g.x);
        acc0.y += v * bfhi(g.x);
        acc0.z += v * bflo(g.y);
        acc0.w += v * bfhi(g.y);
        acc1.x += v * bflo(g.z);
        acc1.y += v * bfhi(g.z);
        acc1.z += v * bflo(g.w);
        acc1.w += v * bfhi(g.w);
    }

    // norm reduce across the 8 lanes of this sub (xor masks < 8 stay in-sub)
    float ss = acc0.x * acc0.x + acc0.y * acc0.y + acc0.z * acc0.z + acc0.w * acc0.w
             + acc1.x * acc1.x + acc1.y * acc1.y + acc1.z * acc1.z + acc1.w * acc1.w;
    ss += __shfl_xor(ss, 1, 64);
    ss += __shfl_xor(ss, 2, 64);
    ss += __shfl_xor(ss, 4, 64);
    float inv = 1.0f / fmaxf(sqrtf(ss), 1e-12f);

    uint4 o;
    o.x = pack_bf16x2(acc0.x * inv, acc0.y * inv);
    o.y = pack_bf16x2(acc0.z * inv, acc0.w * inv);
    o.z = pack_bf16x2(acc1.x * inv, acc1.y * inv);
    o.w = pack_bf16x2(acc1.z * inv, acc1.w * inv);
    ((uint4*)(nxt + (size_t)row * 32))[q] = o;
}

// Final pull: layer-3 propagation fused with the 4-layer mean.
// out[row] = (e0_fp32 + e1 + e2 + normalize(gather)) * 0.25
__global__ void lg_pull_final(const int* __restrict__ offs, const int2* __restrict__ edges,
                              const u32* __restrict__ src,      // e2 table (gather source)
                              const float4* __restrict__ user, const float4* __restrict__ item,
                              int nU,
                              const u32* __restrict__ e1b,
                              float4* __restrict__ out, int n) {
    int row = blockIdx.x * 32 + (threadIdx.x >> 3);
    if (row >= n) return;
    int q = threadIdx.x & 7;

    int beg = offs[row];
    int end = offs[row + 1];
    float4 acc0 = make_float4(0.f, 0.f, 0.f, 0.f);
    float4 acc1 = make_float4(0.f, 0.f, 0.f, 0.f);

    int j = beg;
    for (; j + 8 <= end; j += 8) {
        int2 e[8];
        #pragma unroll
        for (int k = 0; k < 8; ++k) e[k] = edges[j + k];
        uint4 g[8];
        #pragma unroll
        for (int k = 0; k < 8; ++k)
            g[k] = ((const uint4*)(src + (size_t)e[k].x * 32))[q];
        #pragma unroll
        for (int k = 0; k < 8; ++k) {
            float v = __int_as_float(e[k].y);
            acc0.x += v * bflo(g[k].x);
            acc0.y += v * bfhi(g[k].x);
            acc0.z += v * bflo(g[k].y);
            acc0.w += v * bfhi(g[k].y);
            acc1.x += v * bflo(g[k].z);
            acc1.y += v * bfhi(g[k].z);
            acc1.z += v * bflo(g[k].w);
            acc1.w += v * bfhi(g[k].w);
        }
    }
    for (; j + 4 <= end; j += 4) {
        int2 e[4];
        #pragma unroll
        for (int k = 0; k < 4; ++k) e[k] = edges[j + k];
        uint4 g[4];
        #pragma unroll
        for (int k = 0; k < 4; ++k)
            g[k] = ((const uint4*)(src + (size_t)e[k].x * 32))[q];
        #pragma unroll
        for (int k = 0; k < 4; ++k) {
            float v = __int_as_float(e[k].y);
            acc0.x += v * bflo(g[k].x);
            acc0.y += v * bfhi(g[k].x);
            acc0.z += v * bflo(g[k].y);
            acc0.w += v * bfhi(g[k].y);
            acc1.x += v * bflo(g[k].z);
            acc1.y += v * bfhi(g[k].z);
            acc1.z += v * bflo(g[k].w);
            acc1.w += v * bfhi(g[k].w);
        }
    }
    for (; j < end; ++j) {
        int2 e = edges[j];
        uint4 g = ((const uint4*)(src + (size_t)e.x * 32))[q];
        float v = __int_as_float(e.y);
        acc0.x += v * bflo(g.x);
        acc0.y += v * bfhi(g.x);
        acc0.z += v * bflo(g.y);
        acc0.w += v * bfhi(g.y);
        acc1.x += v * bflo(g.z);
        acc1.y += v * bfhi(g.z);
        acc1.z += v * bflo(g.w);
        acc1.w += v * bfhi(g.w);
    }

    float ss = acc0.x * acc0.x + acc0.y * acc0.y + acc0.z * acc0.z + acc0.w * acc0.w
             + acc1.x * acc1.x + acc1.y * acc1.y + acc1.z * acc1.z + acc1.w * acc1.w;
    ss += __shfl_xor(ss, 1, 64);
    ss += __shfl_xor(ss, 2, 64);
    ss += __shfl_xor(ss, 4, 64);
    float inv = 1.0f / fmaxf(sqrtf(ss), 1e-12f);

    float4 aLo, aHi;
    if (row < nU) {
        aLo = user[(size_t)row * 16 + 2 * q];
        aHi = user[(size_t)row * 16 + 2 * q + 1];
    } else {
        aLo = item[(size_t)(row - nU) * 16 + 2 * q];
        aHi = item[(size_t)(row - nU) * 16 + 2 * q + 1];
    }
    uint4 b1 = ((const uint4*)(e1b + (size_t)row * 32))[q];
    uint4 b2 = ((const uint4*)(src + (size_t)row * 32))[q];
    float4 r0, r1;
    r0.x = (aLo.x + bflo(b1.x) + bflo(b2.x) + acc0.x * inv) * 0.25f;
    r0.y = (aLo.y + bfhi(b1.x) + bfhi(b2.x) + acc0.y * inv) * 0.25f;
    r0.z = (aLo.z + bflo(b1.y) + bflo(b2.y) + acc0.z * inv) * 0.25f;
    r0.w = (aLo.w + bfhi(b1.y) + bfhi(b2.y) + acc0.w * inv) * 0.25f;
    r1.x = (aHi.x + bflo(b1.z) + bflo(b2.z) + acc1.x * inv) * 0.25f;
    r1.y = (aHi.y + bfhi(b1.z) + bfhi(b2.z) + acc1.y * inv) * 0.25f;
    r1.z = (aHi.z + bflo(b1.w) + bflo(b2.w) + acc1.z * inv) * 0.25f;
    r1.w = (aHi.w + bfhi(b1.w) + bfhi(b2.w) + acc1.w * inv) * 0.25f;
    out[(size_t)row * 16 + 2 * q] = r0;
    out[(size_t)row * 16 + 2 * q + 1] = r1;
}

// ---------------- fallback (atomic-scatter fp32 path) ----------------

__global__ void lg_init(const float4* __restrict__ user, const float4* __restrict__ item,
                        float4* __restrict__ cur, float4* __restrict__ sum,
                        int user_vec4, int total_vec4) {
    int i = blockIdx.x * blockDim.x + threadIdx.x;
    if (i >= total_vec4) return;
    float4 v = (i < user_vec4) ? user[i] : item[i - user_vec4];
    cur[i] = v;
    sum[i] = v;
}

__global__ void lg_scatter(const int* __restrict__ rows, const int* __restrict__ cols,
                           const float* __restrict__ vals,
                           const float* __restrict__ cur, float* __restrict__ next,
                           int nnz) {
    int gid = blockIdx.x * blockDim.x + threadIdx.x;
    int e = gid >> 6;
    int d = gid & 63;
    if (e >= nnz) return;
    atomicAdd(&next[rows[e] * D + d], vals[e] * cur[cols[e] * D + d]);
}

__global__ void lg_norm_acc(float* __restrict__ emb, float* __restrict__ sum, int n) {
    int row = blockIdx.x * (blockDim.x >> 6) + (threadIdx.x >> 6);
    int d = threadIdx.x & 63;
    if (row >= n) return;
    int idx = row * D + d;
    float v = emb[idx];
    float ss = v * v;
    #pragma unroll
    for (int off = 32; off > 0; off >>= 1) ss += __shfl_xor(ss, off, 64);
    float out = v / fmaxf(sqrtf(ss), 1e-12f);
    emb[idx] = out;
    sum[idx] += out;
}

__global__ void lg_final(float4* __restrict__ out, int n4) {
    int i = blockIdx.x * blockDim.x + threadIdx.x;
    if (i >= n4) return;
    float4 s = out[i];
    out[i] = make_float4(s.x * 0.25f, s.y * 0.25f, s.z * 0.25f, s.w * 0.25f);
}

// ---------------- launch ----------------

extern "C" void kernel_launch(void* const* d_in, const int* in_sizes, int n_in,
                              void* d_out, int out_size, void* d_ws, size_t ws_size,
                              hipStream_t stream) {
    const float* user = (const float*)d_in[0];
    const float* item = (const float*)d_in[1];
    const float* vals = (const float*)d_in[2];
    const int*   rows = (const int*)d_in[3];
    const int*   cols = (const int*)d_in[4];

    const int nU  = in_sizes[0] / D;
    const int nI  = in_sizes[1] / D;
    const int N   = nU + nI;
    const int nnz = in_sizes[2];

    const size_t embElems = (size_t)N * D;
    const size_t embU32   = (size_t)N * 32;
    const int total4 = (int)(embElems / 4);
    float* out = (float*)d_out;

    const int nbuck = (N + ROWS_PER_BUCKET - 1) / ROWS_PER_BUCKET;
    // slab capacity: avg + 1024 (~11 sigma for uniform rows), 64-aligned
    int cap = (nnz + nbuck - 1) / nbuck + 1024;
    cap = (cap + 63) & ~63;

    // ws layout
    char* p = (char*)d_ws;
    u32* t0  = (u32*)p;           p = align16(p + embU32 * sizeof(u32));
    u32* e1b = (u32*)p;           p = align16(p + embU32 * sizeof(u32));
    u32* e2b = (u32*)p;           p = align16(p + embU32 * sizeof(u32));
    int* counts   = (int*)p;      p = align16(p + (size_t)N * sizeof(int));     // fallback only
    int* offsets  = (int*)p;      p = align16(p + (size_t)(N + 1) * sizeof(int));
    int* cursor   = (int*)p;      p = align16(p + (size_t)N * sizeof(int));     // fallback only
    int* bucketOffs = (int*)p;    p = align16(p + (NBUCK_MAX + 1) * sizeof(int));
    int* bucketCursor = (int*)p;  p = align16(p + NBUCK_MAX * sizeof(int));
    u64* edges    = (u64*)p;      p = align16(p + (size_t)nnz * sizeof(u64));
    size_t needNoTmp = (size_t)(p - (char*)d_ws);
    u64* tmp      = (u64*)p;      p = align16(p + (size_t)nbuck * (size_t)cap * sizeof(u64));
    size_t needBytes = (size_t)(p - (char*)d_ws);

    if (ws_size >= needNoTmp) {
        lg_to_bf16<<<(total4 + 255) / 256, 256, 0, stream>>>(
            (const float4*)user, (const float4*)item, (uint2*)t0, nU * D / 4, total4);

        if (nbuck <= NBUCK_MAX && ws_size >= needBytes) {
            hipMemsetAsync(bucketCursor, 0, (size_t)nbuck * sizeof(int), stream);
            int ab = (nnz + BINA_CHUNK - 1) / BINA_CHUNK;
            lg_binA<<<ab, BINA_THREADS, 0, stream>>>(rows, cols, vals, bucketCursor,
                                                     tmp, nnz, nbuck, cap);
            lg_cscan<<<1, 1024, 0, stream>>>(bucketCursor, bucketOffs,
                                             offsets + N, nbuck, cap);
            lg_binB2<<<nbuck, 512, 0, stream>>>(bucketCursor, bucketOffs, tmp,
                                                offsets, (int2*)edges, N, cap);
        } else {
            hipMemsetAsync(counts, 0, (size_t)N * sizeof(int), stream);
            int eb = (nnz + 255) / 256;
            lg_hist<<<eb, 256, 0, stream>>>(rows, counts, nnz);
            lg_scan1<<<1, 1024, 0, stream>>>(counts, offsets, cursor, N);
            lg_fill<<<eb, 256, 0, stream>>>(rows, cols, vals, cursor, edges, nnz);
        }

        // ---- layers 1,2 bf16; layer 3 fused with mean ----
        int rb = (N + 31) / 32;
        lg_pull_bf16<<<rb, 256, 0, stream>>>(offsets, (const int2*)edges, t0,  e1b, N);
        lg_pull_bf16<<<rb, 256, 0, stream>>>(offsets, (const int2*)edges, e1b, e2b, N);
        lg_pull_final<<<rb, 256, 0, stream>>>(offsets, (const int2*)edges, e2b,
                                              (const float4*)user, (const float4*)item, nU,
                                              e1b, (float4*)out, N);
    } else {
        // fallback: fp32 atomic scatter
        float* buf0 = (float*)t0;
        float* buf1 = buf0 + embElems;
        float* sum  = out;
        lg_init<<<(total4 + 255) / 256, 256, 0, stream>>>(
            (const float4*)user, (const float4*)item,
            (float4*)buf0, (float4*)sum, nU * D / 4, total4);
        float* cur = buf0;
        float* nxt = buf1;
        for (int layer = 0; layer < 3; ++layer) {
            hipMemsetAsync(nxt, 0, embElems * sizeof(float), stream);
            int totThreads = nnz * 64;
            int blocks = (totThreads + 255) / 256;
            lg_scatter<<<blocks, 256, 0, stream>>>(rows, cols, vals, cur, nxt, nnz);
            lg_norm_acc<<<(N + 3) / 4, 256, 0, stream>>>(nxt, sum, N);
            float* t = cur; cur = nxt; nxt = t;
        }
        lg_final<<<(total4 + 255) / 256, 256, 0, stream>>>((float4*)sum, total4);
    }
}